// Round 7
// baseline (156.275 us; speedup 1.0000x reference)
//
#include <hip/hip_runtime.h>
#include <cfloat>

// VectorQuantizer: inputs [65536,64] f32, embeddings [2048,64] f32
#define N_TOTAL 65536
#define DIM     64
#define NEMB    2048

typedef __attribute__((ext_vector_type(8))) _Float16 half8;   // MFMA A/B frag (4 VGPRs)
typedef __attribute__((ext_vector_type(4))) float    floatx4; // MFMA C/D frag

// ---------------------------------------------------------------------------
// Prep: pack embeddings as f16 in MFMA-B frag-major layout
//   chunk c = (g*2 + ks)*64 + lane, lane = q*16 + n:
//   ehp[c] = e_f16[col = g*16+n][k = ks*32 + q*8 .. +8)
// One 16-col sub = 2 chunks = 2 KB contiguous. Also fp32 norms -> en[2048].
// ---------------------------------------------------------------------------
__global__ void prep_kernel(const float* __restrict__ emb,
                            half8* __restrict__ ehp, float* __restrict__ en) {
    const int t = blockIdx.x * 256 + threadIdx.x;   // 16384 threads
    {
        const int l   = t & 63;
        const int ks  = (t >> 6) & 1;
        const int g   = t >> 7;
        const int col = g * 16 + (l & 15);
        const int kb  = ks * 32 + (l >> 4) * 8;
        const float* s = emb + col * DIM + kb;
        float4 v0 = *(const float4*)s, v1 = *(const float4*)(s + 4);
        half8 hv;
        hv[0] = (_Float16)v0.x; hv[1] = (_Float16)v0.y;
        hv[2] = (_Float16)v0.z; hv[3] = (_Float16)v0.w;
        hv[4] = (_Float16)v1.x; hv[5] = (_Float16)v1.y;
        hv[6] = (_Float16)v1.z; hv[7] = (_Float16)v1.w;
        ehp[t] = hv;
    }
    if (t < NEMB * 4) {
        const int row = t >> 2, seg = t & 3;
        const float* s = emb + row * DIM + seg * 16;
        float acc = 0.f;
#pragma unroll
        for (int i = 0; i < 4; ++i) {
            float4 v = ((const float4*)s)[i];
            acc = fmaf(v.x, v.x, acc); acc = fmaf(v.y, v.y, acc);
            acc = fmaf(v.z, v.z, acc); acc = fmaf(v.w, v.w, acc);
        }
        acc += __shfl_xor(acc, 1, 64);
        acc += __shfl_xor(acc, 2, 64);
        if (seg == 0) en[row] = acc;
    }
}

// ---------------------------------------------------------------------------
// Main. Block = 4 waves, 64 rows, 1024 blocks.
//   THIS ROUND: wave = COLUMN-QUARTER (was: wave-pairs duplicating the
//   B-stream). Each wave scans cols [w*512, +512) = 32 subs for ALL 64
//   rows (4 row-tiles in registers). Per block the B-stream is now read
//   once (was twice); per wave: subs 64->32 so VMEM instrs and per-sub
//   scaffolding VALU halve; MFMA + top-2 totals unchanged. R6 showed dur
//   tracks issue-cycle demand ~1:1 (latency levers R2/R4/R5 all null).
//   Register budget: single-limb A (32), sbuf depth-2 (16), best/sec[16]
//   (32) -> ~115 live, fits bounds(256,4)'s 128 cap without spill.
//   approx q = x_f16 . e_f16 - ||e||^2/2 + 128
//   packed key = (bits(q) & ~63) | (63-L); 3-op top-2 update
//     (v_and_or_b32 / v_max_u32 / v_med3_u32), immediate (deferral null).
//   Epilogue: top-2 per quarter -> 8 candidates/row, exact fp32 rescore.
// ---------------------------------------------------------------------------
__global__ __launch_bounds__(256, 4) void vq_mfma_kernel(
        const float* __restrict__ x, const float* __restrict__ emb,
        const char* __restrict__ ehb, const float* __restrict__ eng,
        float* __restrict__ quant, float* __restrict__ idxf,
        float* __restrict__ flat) {

    __shared__ uint4 Mrg[4][64];         // 4 KB: per-quarter top-2 candidates

    const int t    = threadIdx.x;
    const int wave = t >> 6, lane = t & 63;
    const int n = lane & 15, q = lane >> 4;
    const int blk0 = blockIdx.x * 64;

    // ---- flat_inputs copy (block-coalesced, fire-and-forget stores) ----
    {
        const float4* s4 = (const float4*)(x + (size_t)blk0 * DIM);
        float4*       d4 = (float4*)(flat + (size_t)blk0 * DIM);
#pragma unroll
        for (int i = 0; i < 4; ++i) d4[i * 256 + t] = s4[i * 256 + t];
    }

    // ---- A fragments, f16 single-limb, 4 row-tiles. A[m=lane&15][k=q*8+j] ----
    half8 ah[4][2];
#pragma unroll
    for (int tl = 0; tl < 4; ++tl)
#pragma unroll
        for (int ks = 0; ks < 2; ++ks) {
            const float* pp = x + (size_t)(blk0 + tl * 16 + n) * DIM + ks * 32 + q * 8;
            float4 v0 = *(const float4*)pp, v1 = *(const float4*)(pp + 4);
            float xv[8] = {v0.x, v0.y, v0.z, v0.w, v1.x, v1.y, v1.z, v1.w};
#pragma unroll
            for (int j = 0; j < 8; ++j)
                ah[tl][ks][j] = (_Float16)xv[j];
        }

    // key-pack mask pinned in a VGPR: v_and_or_b32 then needs only the
    // uniform Lp as its one SGPR operand -> 1 instr per element.
    unsigned maskv;
    asm("v_mov_b32 %0, 0xFFFFFFC0" : "=v"(maskv));

    unsigned best[16], sec[16];
#pragma unroll
    for (int r = 0; r < 16; ++r) { best[r] = 0u; sec[r] = 0u; }

    // per-lane stream base: quarter w = 32 subs x 2 KB = 64 KB contiguous
    const char*  ebase = ehb + (size_t)wave * 65536 + (size_t)lane * 16;
    const float* enp   = eng + wave * 512 + n;   // norms direct from L2

    half8 sbuf[2][2];
    float enc[2];
    // ---- prologue: subs 0,1 into buffers 0,1 ----
#pragma unroll
    for (int j = 0; j < 2; ++j) {
        const char* src = ebase + (size_t)j * 2048;
        sbuf[j][0] = *(const half8*)(src);
        sbuf[j][1] = *(const half8*)(src + 1024);
        enc[j]     = enp[j * 16];
    }

#pragma unroll 2
    for (int i = 0; i < 32; ++i) {
        const int buf = i & 1;          // static under unroll 2

        const float enh = fmaf(-0.5f, enc[buf], 128.0f);
        floatx4 e4 = {enh, enh, enh, enh};
        half8 bk0 = sbuf[buf][0];
        half8 bk1 = sbuf[buf][1];
        __builtin_amdgcn_s_setprio(1);
        floatx4 a0 = __builtin_amdgcn_mfma_f32_16x16x32_f16(ah[0][0], bk0, e4, 0, 0, 0);
        floatx4 a1 = __builtin_amdgcn_mfma_f32_16x16x32_f16(ah[1][0], bk0, e4, 0, 0, 0);
        floatx4 a2 = __builtin_amdgcn_mfma_f32_16x16x32_f16(ah[2][0], bk0, e4, 0, 0, 0);
        floatx4 a3 = __builtin_amdgcn_mfma_f32_16x16x32_f16(ah[3][0], bk0, e4, 0, 0, 0);
        a0 = __builtin_amdgcn_mfma_f32_16x16x32_f16(ah[0][1], bk1, a0, 0, 0, 0);
        a1 = __builtin_amdgcn_mfma_f32_16x16x32_f16(ah[1][1], bk1, a1, 0, 0, 0);
        a2 = __builtin_amdgcn_mfma_f32_16x16x32_f16(ah[2][1], bk1, a2, 0, 0, 0);
        a3 = __builtin_amdgcn_mfma_f32_16x16x32_f16(ah[3][1], bk1, a3, 0, 0, 0);
        __builtin_amdgcn_s_setprio(0);

        // refill the just-consumed buffer with sub i+2 (independent of the
        // update below; compiler schedules the loads under it)
        if (i < 30) {
            const char* src = ebase + (size_t)(i + 2) * 2048;
            sbuf[buf][0] = *(const half8*)(src);
            sbuf[buf][1] = *(const half8*)(src + 1024);
            enc[buf]     = enp[(i + 2) * 16];
        }

        const unsigned Lp = (unsigned)(63 - i);
#pragma unroll
        for (int r = 0; r < 16; ++r) {
            float v = (r < 4) ? a0[r] : (r < 8) ? a1[r - 4]
                    : (r < 12) ? a2[r - 8] : a3[r - 12];
            unsigned key = (__float_as_uint(v) & maskv) | Lp;  // v_and_or_b32
            unsigned nb  = best[r] > key ? best[r] : key;      // v_max_u32
            unsigned ns;
            // invariant best>=sec: new sec == median(best, sec, key)
            asm("v_med3_u32 %0, %1, %2, %3"
                : "=v"(ns) : "v"(best[r]), "v"(sec[r]), "v"(key));
            sec[r]  = ns;
            best[r] = nb;
        }
    }

    // ---- decode per-lane top-2 to (bucketed bits, full col) ----
    // slot r: row = (r>>2)*16 + q*4 + (r&3); tag = 63-L -> col = w*512+L*16+n
    unsigned bval[16], bcol[16], sval[16], scol[16];
#pragma unroll
    for (int r = 0; r < 16; ++r) {
        bval[r] = best[r] & 0xFFFFFFC0u;
        bcol[r] = (unsigned)(wave * 512 + (63 - (int)(best[r] & 63u)) * 16 + n);
        sval[r] = sec[r] & 0xFFFFFFC0u;
        scol[r] = (unsigned)(wave * 512 + (63 - (int)(sec[r] & 63u)) * 16 + n);
    }
    // ---- butterfly top-2 merge across the 16 n-lanes of each q-group ----
#pragma unroll
    for (int m = 1; m < 16; m <<= 1) {
#pragma unroll
        for (int r = 0; r < 16; ++r) {
            unsigned ov  = (unsigned)__shfl_xor((int)bval[r], m, 64);
            unsigned oc  = (unsigned)__shfl_xor((int)bcol[r], m, 64);
            unsigned ov2 = (unsigned)__shfl_xor((int)sval[r], m, 64);
            unsigned oc2 = (unsigned)__shfl_xor((int)scol[r], m, 64);
            bool ow = (ov > bval[r]) || (ov == bval[r] && oc < bcol[r]);
            unsigned nbv = ow ? ov : bval[r], nbc = ow ? oc : bcol[r];
            unsigned lv  = ow ? bval[r] : ov, lc  = ow ? bcol[r] : oc;
            bool sv2 = (ov2 > sval[r]) || (ov2 == sval[r] && oc2 < scol[r]);
            unsigned bsv = sv2 ? ov2 : sval[r], bsc = sv2 ? oc2 : scol[r];
            bool s3 = (lv > bsv) || (lv == bsv && lc < bsc);
            sval[r] = s3 ? lv : bsv; scol[r] = s3 ? lc : bsc;
            bval[r] = nbv; bcol[r] = nbc;
        }
    }
    // ---- publish per-quarter candidates ----
    if (n == 0) {
#pragma unroll
        for (int r = 0; r < 16; ++r) {
            const int lr = (r >> 2) * 16 + q * 4 + (r & 3);
            Mrg[wave][lr] = make_uint4(bval[r], bcol[r], sval[r], scol[r]);
        }
    }
    __syncthreads();

    // ---- exact fp32 rescore of 8 candidates; wave handles 16 rows,
    //      each 16-lane q-group owns 4 rows ----
#pragma unroll
    for (int rr = 0; rr < 4; ++rr) {
        const int lr   = wave * 16 + q * 4 + rr;
        const int grow = blk0 + lr;
        uint4 c0v = Mrg[0][lr], c1v = Mrg[1][lr];
        uint4 c2v = Mrg[2][lr], c3v = Mrg[3][lr];
        // mask to valid range: never fires when slots saw real updates; if a
        // slot stayed 0 the masked row is a legit competitor that can only
        // win when the candidate set already missed the global argmin.
        int cand[8] = {(int)(c0v.y & 2047u), (int)(c0v.w & 2047u),
                       (int)(c1v.y & 2047u), (int)(c1v.w & 2047u),
                       (int)(c2v.y & 2047u), (int)(c2v.w & 2047u),
                       (int)(c3v.y & 2047u), (int)(c3v.w & 2047u)};
        float4 xv = *(const float4*)(x + (size_t)grow * DIM + n * 4);
        float pbest = -FLT_MAX; int cbest = 0;
        float4 ebest = {0.f, 0.f, 0.f, 0.f};
#pragma unroll
        for (int c = 0; c < 8; ++c) {
            float4 e = *(const float4*)(emb + (size_t)cand[c] * DIM + n * 4);
            float pp = (xv.x - 0.5f * e.x) * e.x + (xv.y - 0.5f * e.y) * e.y
                     + (xv.z - 0.5f * e.z) * e.z + (xv.w - 0.5f * e.w) * e.w;
#pragma unroll
            for (int m2 = 1; m2 < 16; m2 <<= 1) pp += __shfl_xor(pp, m2, 64);
            bool take = (pp > pbest) || (pp == pbest && cand[c] < cbest);
            pbest = take ? pp : pbest;
            cbest = take ? cand[c] : cbest;
            ebest.x = take ? e.x : ebest.x; ebest.y = take ? e.y : ebest.y;
            ebest.z = take ? e.z : ebest.z; ebest.w = take ? e.w : ebest.w;
        }
        *(float4*)(quant + (size_t)grow * DIM + n * 4) = ebest;
        if (n == 0) idxf[grow] = (float)cbest;
    }
}

extern "C" void kernel_launch(void* const* d_in, const int* in_sizes, int n_in,
                              void* d_out, int out_size, void* d_ws, size_t ws_size,
                              hipStream_t stream) {
    const float* x   = (const float*)d_in[0];   // [65536, 64]
    const float* emb = (const float*)d_in[1];   // [2048, 64]
    float* out   = (float*)d_out;
    float* quant = out;                               // 4194304 floats
    float* idxf  = out + (size_t)N_TOTAL * DIM;       // 65536 floats
    float* flat  = idxf + N_TOTAL;                    // 4194304 floats

    half8* ehp = (half8*)d_ws;                        // 2048*64 f16 frag-major (256 KB)
    float* en  = (float*)((char*)d_ws + (size_t)NEMB * DIM * 2);  // 2048 f32

    prep_kernel<<<64, 256, 0, stream>>>(emb, ehp, en);
    vq_mfma_kernel<<<N_TOTAL / 64, 256, 0, stream>>>(x, emb, (const char*)ehp, en,
                                                     quant, idxf, flat);
}

// Round 8
// 112.441 us; speedup vs baseline: 1.3898x; 1.3898x over previous
//
#include <hip/hip_runtime.h>
#include <cfloat>

// VectorQuantizer: inputs [65536,64] f32, embeddings [2048,64] f32
#define N_TOTAL 65536
#define DIM     64
#define NEMB    2048

typedef __attribute__((ext_vector_type(8))) _Float16 half8;   // MFMA A/B frag (4 VGPRs)
typedef __attribute__((ext_vector_type(4))) float    floatx4; // MFMA C/D frag

// ---------------------------------------------------------------------------
// Prep: pack embeddings as f16 in MFMA frag-major layout (role-agnostic:
// A- and B-frag lane mappings are identical).
//   chunk c = (g*2 + ks)*64 + lane, lane = q*16 + n:
//   ehp[c] = e_f16[col = g*16+n][k = ks*32 + q*8 .. +8)
// One 16-col sub = 2 chunks = 2 KB contiguous. Also fp32 norms -> en[2048].
// ---------------------------------------------------------------------------
__global__ void prep_kernel(const float* __restrict__ emb,
                            half8* __restrict__ ehp, float* __restrict__ en) {
    const int t = blockIdx.x * 256 + threadIdx.x;   // 16384 threads
    {
        const int l   = t & 63;
        const int ks  = (t >> 6) & 1;
        const int g   = t >> 7;
        const int col = g * 16 + (l & 15);
        const int kb  = ks * 32 + (l >> 4) * 8;
        const float* s = emb + col * DIM + kb;
        float4 v0 = *(const float4*)s, v1 = *(const float4*)(s + 4);
        half8 hv;
        hv[0] = (_Float16)v0.x; hv[1] = (_Float16)v0.y;
        hv[2] = (_Float16)v0.z; hv[3] = (_Float16)v0.w;
        hv[4] = (_Float16)v1.x; hv[5] = (_Float16)v1.y;
        hv[6] = (_Float16)v1.z; hv[7] = (_Float16)v1.w;
        ehp[t] = hv;
    }
    if (t < NEMB * 4) {
        const int row = t >> 2, seg = t & 3;
        const float* s = emb + row * DIM + seg * 16;
        float acc = 0.f;
#pragma unroll
        for (int i = 0; i < 4; ++i) {
            float4 v = ((const float4*)s)[i];
            acc = fmaf(v.x, v.x, acc); acc = fmaf(v.y, v.y, acc);
            acc = fmaf(v.z, v.z, acc); acc = fmaf(v.w, v.w, acc);
        }
        acc += __shfl_xor(acc, 1, 64);
        acc += __shfl_xor(acc, 2, 64);
        if (seg == 0) en[row] = acc;
    }
}

// ---------------------------------------------------------------------------
// Main. Block = 4 waves, 64 rows, 1024 blocks.
//   THIS ROUND: wave = column-quarter (B-stream dedup, halved per-wave VMEM
//   + per-sub scaffolding) WITHOUT R7's spill, via SWAPPED MFMA operands:
//   D = mfma(E_frag, X_frag, C). C/D layout => lane's x-row is FIXED
//   (lane&15); its 4 regs are 4 e-cols. Trackers: 4 pairs (one per x-tile),
//   not R7's 16. The e-norm bias enters through the MFMA C-operand as a
//   true per-reg float4 (one dwordx4 norm load per sub, zero per-element
//   bias VALU).
//   approx q = x_f16 . e_f16 - ||e||^2/2 + 128
//   packed key = (bits(q) & ~127) | ((31-i)<<2 | (3-r)); 3-op top-2 update
//     (v_and_or_b32 / v_max_u32 / v_med3_u32), immediate (deferral null).
//   Epilogue: 2-step butterfly over q-lanes; top-2 per quarter -> 8
//   candidates/row, exact fp32 rescore (R7's proven epilogue).
// ---------------------------------------------------------------------------
__global__ __launch_bounds__(256, 4) void vq_mfma_kernel(
        const float* __restrict__ x, const float* __restrict__ emb,
        const char* __restrict__ ehb, const float* __restrict__ eng,
        float* __restrict__ quant, float* __restrict__ idxf,
        float* __restrict__ flat) {

    __shared__ uint4 Mrg[4][64];         // 4 KB: per-quarter top-2 candidates

    const int t    = threadIdx.x;
    const int wave = t >> 6, lane = t & 63;
    const int n = lane & 15, q = lane >> 4;
    const int blk0 = blockIdx.x * 64;

    // ---- flat_inputs copy (block-coalesced, fire-and-forget stores) ----
    {
        const float4* s4 = (const float4*)(x + (size_t)blk0 * DIM);
        float4*       d4 = (float4*)(flat + (size_t)blk0 * DIM);
#pragma unroll
        for (int i = 0; i < 4; ++i) d4[i * 256 + t] = s4[i * 256 + t];
    }

    // ---- X fragments (MFMA B-operand role), f16 single-limb, 4 row-tiles.
    //      xf[tl][ks]: x[row = tl*16 + (lane&15)][k = ks*32 + q*8 + j] ----
    half8 xf[4][2];
#pragma unroll
    for (int tl = 0; tl < 4; ++tl)
#pragma unroll
        for (int ks = 0; ks < 2; ++ks) {
            const float* pp = x + (size_t)(blk0 + tl * 16 + n) * DIM + ks * 32 + q * 8;
            float4 v0 = *(const float4*)pp, v1 = *(const float4*)(pp + 4);
            float xv[8] = {v0.x, v0.y, v0.z, v0.w, v1.x, v1.y, v1.z, v1.w};
#pragma unroll
            for (int j = 0; j < 8; ++j)
                xf[tl][ks][j] = (_Float16)xv[j];
        }

    // key-pack mask pinned in a VGPR: v_and_or_b32 then needs only the
    // uniform tag as its one SGPR operand -> 1 instr per element.
    unsigned maskv;
    asm("v_mov_b32 %0, 0xFFFFFF80" : "=v"(maskv));

    unsigned best[4], sec[4];
#pragma unroll
    for (int r = 0; r < 4; ++r) { best[r] = 0u; sec[r] = 0u; }

    // per-lane stream base: quarter w = 32 subs x 2 KB = 64 KB contiguous
    const char*  ebase = ehb + (size_t)wave * 65536 + (size_t)lane * 16;
    const float* enp   = eng + wave * 512 + q * 4;   // float4 of norms per sub

    half8  sbuf[2][2];
    float4 enc4[2];
    // ---- prologue: subs 0,1 into buffers 0,1 ----
#pragma unroll
    for (int j = 0; j < 2; ++j) {
        const char* src = ebase + (size_t)j * 2048;
        sbuf[j][0] = *(const half8*)(src);
        sbuf[j][1] = *(const half8*)(src + 1024);
        enc4[j]    = *(const float4*)(enp + j * 16);
    }

#pragma unroll 2
    for (int i = 0; i < 32; ++i) {
        const int buf = i & 1;          // static under unroll 2

        // bias C-tuple: e4[r] = -0.5*||e_{q*4+r}||^2 + 128, shared by all
        // 4 chains (bias depends only on e-col, not x-row).
        floatx4 e4;
        e4[0] = fmaf(-0.5f, enc4[buf].x, 128.0f);
        e4[1] = fmaf(-0.5f, enc4[buf].y, 128.0f);
        e4[2] = fmaf(-0.5f, enc4[buf].z, 128.0f);
        e4[3] = fmaf(-0.5f, enc4[buf].w, 128.0f);
        half8 ek0 = sbuf[buf][0];
        half8 ek1 = sbuf[buf][1];
        __builtin_amdgcn_s_setprio(1);
        floatx4 a0 = __builtin_amdgcn_mfma_f32_16x16x32_f16(ek0, xf[0][0], e4, 0, 0, 0);
        floatx4 a1 = __builtin_amdgcn_mfma_f32_16x16x32_f16(ek0, xf[1][0], e4, 0, 0, 0);
        floatx4 a2 = __builtin_amdgcn_mfma_f32_16x16x32_f16(ek0, xf[2][0], e4, 0, 0, 0);
        floatx4 a3 = __builtin_amdgcn_mfma_f32_16x16x32_f16(ek0, xf[3][0], e4, 0, 0, 0);
        a0 = __builtin_amdgcn_mfma_f32_16x16x32_f16(ek1, xf[0][1], a0, 0, 0, 0);
        a1 = __builtin_amdgcn_mfma_f32_16x16x32_f16(ek1, xf[1][1], a1, 0, 0, 0);
        a2 = __builtin_amdgcn_mfma_f32_16x16x32_f16(ek1, xf[2][1], a2, 0, 0, 0);
        a3 = __builtin_amdgcn_mfma_f32_16x16x32_f16(ek1, xf[3][1], a3, 0, 0, 0);
        __builtin_amdgcn_s_setprio(0);

        // refill the just-consumed buffer with sub i+2
        if (i < 30) {
            const char* src = ebase + (size_t)(i + 2) * 2048;
            sbuf[buf][0] = *(const half8*)(src);
            sbuf[buf][1] = *(const half8*)(src + 1024);
            enc4[buf]    = *(const float4*)(enp + (i + 2) * 16);
        }

        // tags: slot-uniform SGPR values; tag_r = ((31-i)<<2) | (3-r).
        // Higher tag wins ties => lower sub / lower reg => lower col. ✓
        const unsigned tb = (unsigned)((31 - i) << 2);
#pragma unroll
        for (int tl = 0; tl < 4; ++tl) {
            floatx4 av = (tl == 0) ? a0 : (tl == 1) ? a1 : (tl == 2) ? a2 : a3;
#pragma unroll
            for (int r = 0; r < 4; ++r) {
                unsigned key = (__float_as_uint(av[r]) & maskv) | (tb + (3 - r));
                unsigned nb  = best[tl] > key ? best[tl] : key;     // v_max_u32
                unsigned ns;
                // invariant best>=sec: new sec == median(best, sec, key)
                asm("v_med3_u32 %0, %1, %2, %3"
                    : "=v"(ns) : "v"(best[tl]), "v"(sec[tl]), "v"(key));
                sec[tl]  = ns;
                best[tl] = nb;
            }
        }
    }

    // ---- decode per-lane top-2 to (bucketed bits, full col) ----
    // tag u = key&127: sub = 31-(u>>2), reg = 3-(u&3)
    // col = wave*512 + sub*16 + q*4 + reg
    unsigned bval[4], bcol[4], sval[4], scol[4];
#pragma unroll
    for (int r = 0; r < 4; ++r) {
        unsigned ub = best[r] & 127u, us = sec[r] & 127u;
        bval[r] = best[r] & 0xFFFFFF80u;
        bcol[r] = (unsigned)(wave * 512 + (31 - (int)(ub >> 2)) * 16 + q * 4
                             + (3 - (int)(ub & 3u)));
        sval[r] = sec[r] & 0xFFFFFF80u;
        scol[r] = (unsigned)(wave * 512 + (31 - (int)(us >> 2)) * 16 + q * 4
                             + (3 - (int)(us & 3u)));
    }
    // ---- 2-step butterfly top-2 merge across the 4 q-lanes of each row ----
#pragma unroll
    for (int m = 16; m <= 32; m <<= 1) {
#pragma unroll
        for (int r = 0; r < 4; ++r) {
            unsigned ov  = (unsigned)__shfl_xor((int)bval[r], m, 64);
            unsigned oc  = (unsigned)__shfl_xor((int)bcol[r], m, 64);
            unsigned ov2 = (unsigned)__shfl_xor((int)sval[r], m, 64);
            unsigned oc2 = (unsigned)__shfl_xor((int)scol[r], m, 64);
            bool ow = (ov > bval[r]) || (ov == bval[r] && oc < bcol[r]);
            unsigned nbv = ow ? ov : bval[r], nbc = ow ? oc : bcol[r];
            unsigned lv  = ow ? bval[r] : ov, lc  = ow ? bcol[r] : oc;
            bool sv2 = (ov2 > sval[r]) || (ov2 == sval[r] && oc2 < scol[r]);
            unsigned bsv = sv2 ? ov2 : sval[r], bsc = sv2 ? oc2 : scol[r];
            bool s3 = (lv > bsv) || (lv == bsv && lc < bsc);
            sval[r] = s3 ? lv : bsv; scol[r] = s3 ? lc : bsc;
            bval[r] = nbv; bcol[r] = nbc;
        }
    }
    // ---- publish per-quarter candidates: slot r -> row r*16 + n ----
    if (q == 0) {
#pragma unroll
        for (int r = 0; r < 4; ++r)
            Mrg[wave][r * 16 + n] = make_uint4(bval[r], bcol[r], sval[r], scol[r]);
    }
    __syncthreads();

    // ---- exact fp32 rescore of 8 candidates; wave handles 16 rows,
    //      each 16-lane q-group owns 4 rows ----
#pragma unroll
    for (int rr = 0; rr < 4; ++rr) {
        const int lr   = wave * 16 + q * 4 + rr;
        const int grow = blk0 + lr;
        uint4 c0v = Mrg[0][lr], c1v = Mrg[1][lr];
        uint4 c2v = Mrg[2][lr], c3v = Mrg[3][lr];
        int cand[8] = {(int)(c0v.y & 2047u), (int)(c0v.w & 2047u),
                       (int)(c1v.y & 2047u), (int)(c1v.w & 2047u),
                       (int)(c2v.y & 2047u), (int)(c2v.w & 2047u),
                       (int)(c3v.y & 2047u), (int)(c3v.w & 2047u)};
        float4 xv = *(const float4*)(x + (size_t)grow * DIM + n * 4);
        float pbest = -FLT_MAX; int cbest = 0;
        float4 ebest = {0.f, 0.f, 0.f, 0.f};
#pragma unroll
        for (int c = 0; c < 8; ++c) {
            float4 e = *(const float4*)(emb + (size_t)cand[c] * DIM + n * 4);
            float pp = (xv.x - 0.5f * e.x) * e.x + (xv.y - 0.5f * e.y) * e.y
                     + (xv.z - 0.5f * e.z) * e.z + (xv.w - 0.5f * e.w) * e.w;
#pragma unroll
            for (int m2 = 1; m2 < 16; m2 <<= 1) pp += __shfl_xor(pp, m2, 64);
            bool take = (pp > pbest) || (pp == pbest && cand[c] < cbest);
            pbest = take ? pp : pbest;
            cbest = take ? cand[c] : cbest;
            ebest.x = take ? e.x : ebest.x; ebest.y = take ? e.y : ebest.y;
            ebest.z = take ? e.z : ebest.z; ebest.w = take ? e.w : ebest.w;
        }
        *(float4*)(quant + (size_t)grow * DIM + n * 4) = ebest;
        if (n == 0) idxf[grow] = (float)cbest;
    }
}

extern "C" void kernel_launch(void* const* d_in, const int* in_sizes, int n_in,
                              void* d_out, int out_size, void* d_ws, size_t ws_size,
                              hipStream_t stream) {
    const float* x   = (const float*)d_in[0];   // [65536, 64]
    const float* emb = (const float*)d_in[1];   // [2048, 64]
    float* out   = (float*)d_out;
    float* quant = out;                               // 4194304 floats
    float* idxf  = out + (size_t)N_TOTAL * DIM;       // 65536 floats
    float* flat  = idxf + N_TOTAL;                    // 4194304 floats

    half8* ehp = (half8*)d_ws;                        // 2048*64 f16 frag-major (256 KB)
    float* en  = (float*)((char*)d_ws + (size_t)NEMB * DIM * 2);  // 2048 f32

    prep_kernel<<<64, 256, 0, stream>>>(emb, ehp, en);
    vq_mfma_kernel<<<N_TOTAL / 64, 256, 0, stream>>>(x, emb, (const char*)ehp, en,
                                                     quant, idxf, flat);
}

// Round 9
// 111.328 us; speedup vs baseline: 1.4037x; 1.0100x over previous
//
#include <hip/hip_runtime.h>
#include <cfloat>

// VectorQuantizer: inputs [65536,64] f32, embeddings [2048,64] f32
#define N_TOTAL 65536
#define DIM     64
#define NEMB    2048

typedef __attribute__((ext_vector_type(8))) _Float16 half8;   // MFMA A/B frag (4 VGPRs)
typedef __attribute__((ext_vector_type(4))) float    floatx4; // MFMA C/D frag
typedef __attribute__((ext_vector_type(4))) float    f32x4;   // nt-store friendly

// ---------------------------------------------------------------------------
// Prep: pack embeddings as f16 in MFMA frag-major layout (role-agnostic:
// A- and B-frag lane mappings are identical).
//   chunk c = (g*2 + ks)*64 + lane, lane = q*16 + n:
//   ehp[c] = e_f16[col = g*16+n][k = ks*32 + q*8 .. +8)
// One 16-col sub = 2 chunks = 2 KB contiguous. Also fp32 norms -> en[2048].
// ---------------------------------------------------------------------------
__global__ void prep_kernel(const float* __restrict__ emb,
                            half8* __restrict__ ehp, float* __restrict__ en) {
    const int t = blockIdx.x * 256 + threadIdx.x;   // 16384 threads
    {
        const int l   = t & 63;
        const int ks  = (t >> 6) & 1;
        const int g   = t >> 7;
        const int col = g * 16 + (l & 15);
        const int kb  = ks * 32 + (l >> 4) * 8;
        const float* s = emb + col * DIM + kb;
        float4 v0 = *(const float4*)s, v1 = *(const float4*)(s + 4);
        half8 hv;
        hv[0] = (_Float16)v0.x; hv[1] = (_Float16)v0.y;
        hv[2] = (_Float16)v0.z; hv[3] = (_Float16)v0.w;
        hv[4] = (_Float16)v1.x; hv[5] = (_Float16)v1.y;
        hv[6] = (_Float16)v1.z; hv[7] = (_Float16)v1.w;
        ehp[t] = hv;
    }
    if (t < NEMB * 4) {
        const int row = t >> 2, seg = t & 3;
        const float* s = emb + row * DIM + seg * 16;
        float acc = 0.f;
#pragma unroll
        for (int i = 0; i < 4; ++i) {
            float4 v = ((const float4*)s)[i];
            acc = fmaf(v.x, v.x, acc); acc = fmaf(v.y, v.y, acc);
            acc = fmaf(v.z, v.z, acc); acc = fmaf(v.w, v.w, acc);
        }
        acc += __shfl_xor(acc, 1, 64);
        acc += __shfl_xor(acc, 2, 64);
        if (seg == 0) en[row] = acc;
    }
}

// ---------------------------------------------------------------------------
// Main. Block = 4 waves, 64 rows, 1024 blocks. Wave = column-quarter with
// swapped MFMA operands D = mfma(E_frag, X_frag, C): lane's x-row fixed,
// 4 regs = 4 e-cols, trackers = 4 pairs, norm bias enters via C-operand.
//   THIS ROUND: NON-TEMPORAL STORES on all write-once outputs (flat,
//   quant, idxf). Theory: 49 MB of streaming loads/stores allocating in
//   the 4 MB per-XCD L2 keeps evicting the 256 KB packed-E stream, so
//   B-loads run at L3/HBM latency (~500-900 cy) beyond the 2-sub prefetch
//   cover — the ~50% no-issue stall that survived every ILP/TLP lever
//   (R2/R4/R5/R8 nulls). nt stores stop the L2 turnover; loads stay
//   cached (x lines are reused by prologue+rescore; ehp/eng want L2).
//   approx q = x_f16 . e_f16 - ||e||^2/2 + 128
//   packed key = (bits(q) & ~127) | ((31-i)<<2 | (3-r)); 3-op top-2 update
//     (v_and_or_b32 / v_max_u32 / v_med3_u32).
//   Epilogue: 2-step butterfly over q-lanes; top-2 per quarter -> 8
//   candidates/row, exact fp32 rescore.
// ---------------------------------------------------------------------------
__global__ __launch_bounds__(256, 4) void vq_mfma_kernel(
        const float* __restrict__ x, const float* __restrict__ emb,
        const char* __restrict__ ehb, const float* __restrict__ eng,
        float* __restrict__ quant, float* __restrict__ idxf,
        float* __restrict__ flat) {

    __shared__ uint4 Mrg[4][64];         // 4 KB: per-quarter top-2 candidates

    const int t    = threadIdx.x;
    const int wave = t >> 6, lane = t & 63;
    const int n = lane & 15, q = lane >> 4;
    const int blk0 = blockIdx.x * 64;

    // ---- flat_inputs copy: cached loads (x reused below), nt stores ----
    {
        const f32x4* s4 = (const f32x4*)(x + (size_t)blk0 * DIM);
        f32x4*       d4 = (f32x4*)(flat + (size_t)blk0 * DIM);
#pragma unroll
        for (int i = 0; i < 4; ++i) {
            f32x4 v = s4[i * 256 + t];
            __builtin_nontemporal_store(v, &d4[i * 256 + t]);
        }
    }

    // ---- X fragments (MFMA B-operand role), f16 single-limb, 4 row-tiles.
    //      xf[tl][ks]: x[row = tl*16 + (lane&15)][k = ks*32 + q*8 + j] ----
    half8 xf[4][2];
#pragma unroll
    for (int tl = 0; tl < 4; ++tl)
#pragma unroll
        for (int ks = 0; ks < 2; ++ks) {
            const float* pp = x + (size_t)(blk0 + tl * 16 + n) * DIM + ks * 32 + q * 8;
            float4 v0 = *(const float4*)pp, v1 = *(const float4*)(pp + 4);
            float xv[8] = {v0.x, v0.y, v0.z, v0.w, v1.x, v1.y, v1.z, v1.w};
#pragma unroll
            for (int j = 0; j < 8; ++j)
                xf[tl][ks][j] = (_Float16)xv[j];
        }

    // key-pack mask pinned in a VGPR: v_and_or_b32 then needs only the
    // uniform tag as its one SGPR operand -> 1 instr per element.
    unsigned maskv;
    asm("v_mov_b32 %0, 0xFFFFFF80" : "=v"(maskv));

    unsigned best[4], sec[4];
#pragma unroll
    for (int r = 0; r < 4; ++r) { best[r] = 0u; sec[r] = 0u; }

    // per-lane stream base: quarter w = 32 subs x 2 KB = 64 KB contiguous
    const char*  ebase = ehb + (size_t)wave * 65536 + (size_t)lane * 16;
    const float* enp   = eng + wave * 512 + q * 4;   // float4 of norms per sub

    half8  sbuf[2][2];
    float4 enc4[2];
    // ---- prologue: subs 0,1 into buffers 0,1 ----
#pragma unroll
    for (int j = 0; j < 2; ++j) {
        const char* src = ebase + (size_t)j * 2048;
        sbuf[j][0] = *(const half8*)(src);
        sbuf[j][1] = *(const half8*)(src + 1024);
        enc4[j]    = *(const float4*)(enp + j * 16);
    }

#pragma unroll 2
    for (int i = 0; i < 32; ++i) {
        const int buf = i & 1;          // static under unroll 2

        // bias C-tuple: e4[r] = -0.5*||e_{q*4+r}||^2 + 128, shared by all
        // 4 chains (bias depends only on e-col, not x-row).
        floatx4 e4;
        e4[0] = fmaf(-0.5f, enc4[buf].x, 128.0f);
        e4[1] = fmaf(-0.5f, enc4[buf].y, 128.0f);
        e4[2] = fmaf(-0.5f, enc4[buf].z, 128.0f);
        e4[3] = fmaf(-0.5f, enc4[buf].w, 128.0f);
        half8 ek0 = sbuf[buf][0];
        half8 ek1 = sbuf[buf][1];
        __builtin_amdgcn_s_setprio(1);
        floatx4 a0 = __builtin_amdgcn_mfma_f32_16x16x32_f16(ek0, xf[0][0], e4, 0, 0, 0);
        floatx4 a1 = __builtin_amdgcn_mfma_f32_16x16x32_f16(ek0, xf[1][0], e4, 0, 0, 0);
        floatx4 a2 = __builtin_amdgcn_mfma_f32_16x16x32_f16(ek0, xf[2][0], e4, 0, 0, 0);
        floatx4 a3 = __builtin_amdgcn_mfma_f32_16x16x32_f16(ek0, xf[3][0], e4, 0, 0, 0);
        a0 = __builtin_amdgcn_mfma_f32_16x16x32_f16(ek1, xf[0][1], a0, 0, 0, 0);
        a1 = __builtin_amdgcn_mfma_f32_16x16x32_f16(ek1, xf[1][1], a1, 0, 0, 0);
        a2 = __builtin_amdgcn_mfma_f32_16x16x32_f16(ek1, xf[2][1], a2, 0, 0, 0);
        a3 = __builtin_amdgcn_mfma_f32_16x16x32_f16(ek1, xf[3][1], a3, 0, 0, 0);
        __builtin_amdgcn_s_setprio(0);

        // refill the just-consumed buffer with sub i+2
        if (i < 30) {
            const char* src = ebase + (size_t)(i + 2) * 2048;
            sbuf[buf][0] = *(const half8*)(src);
            sbuf[buf][1] = *(const half8*)(src + 1024);
            enc4[buf]    = *(const float4*)(enp + (i + 2) * 16);
        }

        // tags: slot-uniform SGPR values; tag_r = ((31-i)<<2) | (3-r).
        // Higher tag wins ties => lower sub / lower reg => lower col. ✓
        const unsigned tb = (unsigned)((31 - i) << 2);
#pragma unroll
        for (int tl = 0; tl < 4; ++tl) {
            floatx4 av = (tl == 0) ? a0 : (tl == 1) ? a1 : (tl == 2) ? a2 : a3;
#pragma unroll
            for (int r = 0; r < 4; ++r) {
                unsigned key = (__float_as_uint(av[r]) & maskv) | (tb + (3 - r));
                unsigned nb  = best[tl] > key ? best[tl] : key;     // v_max_u32
                unsigned ns;
                // invariant best>=sec: new sec == median(best, sec, key)
                asm("v_med3_u32 %0, %1, %2, %3"
                    : "=v"(ns) : "v"(best[tl]), "v"(sec[tl]), "v"(key));
                sec[tl]  = ns;
                best[tl] = nb;
            }
        }
    }

    // ---- decode per-lane top-2 to (bucketed bits, full col) ----
    // tag u = key&127: sub = 31-(u>>2), reg = 3-(u&3)
    // col = wave*512 + sub*16 + q*4 + reg
    unsigned bval[4], bcol[4], sval[4], scol[4];
#pragma unroll
    for (int r = 0; r < 4; ++r) {
        unsigned ub = best[r] & 127u, us = sec[r] & 127u;
        bval[r] = best[r] & 0xFFFFFF80u;
        bcol[r] = (unsigned)(wave * 512 + (31 - (int)(ub >> 2)) * 16 + q * 4
                             + (3 - (int)(ub & 3u)));
        sval[r] = sec[r] & 0xFFFFFF80u;
        scol[r] = (unsigned)(wave * 512 + (31 - (int)(us >> 2)) * 16 + q * 4
                             + (3 - (int)(us & 3u)));
    }
    // ---- 2-step butterfly top-2 merge across the 4 q-lanes of each row ----
#pragma unroll
    for (int m = 16; m <= 32; m <<= 1) {
#pragma unroll
        for (int r = 0; r < 4; ++r) {
            unsigned ov  = (unsigned)__shfl_xor((int)bval[r], m, 64);
            unsigned oc  = (unsigned)__shfl_xor((int)bcol[r], m, 64);
            unsigned ov2 = (unsigned)__shfl_xor((int)sval[r], m, 64);
            unsigned oc2 = (unsigned)__shfl_xor((int)scol[r], m, 64);
            bool ow = (ov > bval[r]) || (ov == bval[r] && oc < bcol[r]);
            unsigned nbv = ow ? ov : bval[r], nbc = ow ? oc : bcol[r];
            unsigned lv  = ow ? bval[r] : ov, lc  = ow ? bcol[r] : oc;
            bool sv2 = (ov2 > sval[r]) || (ov2 == sval[r] && oc2 < scol[r]);
            unsigned bsv = sv2 ? ov2 : sval[r], bsc = sv2 ? oc2 : scol[r];
            bool s3 = (lv > bsv) || (lv == bsv && lc < bsc);
            sval[r] = s3 ? lv : bsv; scol[r] = s3 ? lc : bsc;
            bval[r] = nbv; bcol[r] = nbc;
        }
    }
    // ---- publish per-quarter candidates: slot r -> row r*16 + n ----
    if (q == 0) {
#pragma unroll
        for (int r = 0; r < 4; ++r)
            Mrg[wave][r * 16 + n] = make_uint4(bval[r], bcol[r], sval[r], scol[r]);
    }
    __syncthreads();

    // ---- exact fp32 rescore of 8 candidates; wave handles 16 rows,
    //      each 16-lane q-group owns 4 rows ----
#pragma unroll
    for (int rr = 0; rr < 4; ++rr) {
        const int lr   = wave * 16 + q * 4 + rr;
        const int grow = blk0 + lr;
        uint4 c0v = Mrg[0][lr], c1v = Mrg[1][lr];
        uint4 c2v = Mrg[2][lr], c3v = Mrg[3][lr];
        int cand[8] = {(int)(c0v.y & 2047u), (int)(c0v.w & 2047u),
                       (int)(c1v.y & 2047u), (int)(c1v.w & 2047u),
                       (int)(c2v.y & 2047u), (int)(c2v.w & 2047u),
                       (int)(c3v.y & 2047u), (int)(c3v.w & 2047u)};
        float4 xv = *(const float4*)(x + (size_t)grow * DIM + n * 4);
        float pbest = -FLT_MAX; int cbest = 0;
        f32x4 ebest = {0.f, 0.f, 0.f, 0.f};
#pragma unroll
        for (int c = 0; c < 8; ++c) {
            float4 e = *(const float4*)(emb + (size_t)cand[c] * DIM + n * 4);
            float pp = (xv.x - 0.5f * e.x) * e.x + (xv.y - 0.5f * e.y) * e.y
                     + (xv.z - 0.5f * e.z) * e.z + (xv.w - 0.5f * e.w) * e.w;
#pragma unroll
            for (int m2 = 1; m2 < 16; m2 <<= 1) pp += __shfl_xor(pp, m2, 64);
            bool take = (pp > pbest) || (pp == pbest && cand[c] < cbest);
            pbest = take ? pp : pbest;
            cbest = take ? cand[c] : cbest;
            ebest.x = take ? e.x : ebest.x; ebest.y = take ? e.y : ebest.y;
            ebest.z = take ? e.z : ebest.z; ebest.w = take ? e.w : ebest.w;
        }
        __builtin_nontemporal_store(ebest, (f32x4*)(quant + (size_t)grow * DIM + n * 4));
        if (n == 0) __builtin_nontemporal_store((float)cbest, &idxf[grow]);
    }
}

extern "C" void kernel_launch(void* const* d_in, const int* in_sizes, int n_in,
                              void* d_out, int out_size, void* d_ws, size_t ws_size,
                              hipStream_t stream) {
    const float* x   = (const float*)d_in[0];   // [65536, 64]
    const float* emb = (const float*)d_in[1];   // [2048, 64]
    float* out   = (float*)d_out;
    float* quant = out;                               // 4194304 floats
    float* idxf  = out + (size_t)N_TOTAL * DIM;       // 65536 floats
    float* flat  = idxf + N_TOTAL;                    // 4194304 floats

    half8* ehp = (half8*)d_ws;                        // 2048*64 f16 frag-major (256 KB)
    float* en  = (float*)((char*)d_ws + (size_t)NEMB * DIM * 2);  // 2048 f32

    prep_kernel<<<64, 256, 0, stream>>>(emb, ehp, en);
    vq_mfma_kernel<<<N_TOTAL / 64, 256, 0, stream>>>(x, emb, (const char*)ehp, en,
                                                     quant, idxf, flat);
}